// Round 3
// baseline (525.217 us; speedup 1.0000x reference)
//
#include <hip/hip_runtime.h>
#include <math.h>

#define NB      16
#define DIM     2048
#define NKVh    8
#define HDIM    64
#define GRP     4
#define MAXSEQ  4096
#define TPOS    4095
#define FFH     5632
#define NSPLIT  8
#define CHUNK   512

// workspace offsets (floats)
#define XN_OFF   0          // 16*2048
#define Q_OFF    32768      // 16*2048 (pre-scaled, roped q)
#define ATTN_OFF 65536      // 16*2048
#define H_OFF    98304      // 16*2048
#define HN_OFF   131072     // 16*2048
#define H1_OFF   163840     // 16*5632
#define H3_OFF   253952     // 16*2048
#define PML_OFF  286720     // 16*8*4*8 * 2
#define PO_OFF   294912     // 16*8*4*8 * 64

__device__ __forceinline__ float dot4(float4 a, float4 b) {
  return a.x * b.x + a.y * b.y + a.z * b.z + a.w * b.w;
}

// ---------------------------------------------------------------- RMSNorm
__global__ __launch_bounds__(256) void rmsnorm_k(const float* __restrict__ x,
    const float* __restrict__ w, float* __restrict__ o) {
  int b = blockIdx.x;
  const float* xr = x + b * DIM;
  float ss = 0.f;
#pragma unroll
  for (int i = 0; i < DIM / 256; ++i) {
    float v = xr[threadIdx.x + i * 256];
    ss += v * v;
  }
#pragma unroll
  for (int m = 32; m >= 1; m >>= 1) ss += __shfl_xor(ss, m, 64);
  __shared__ float sred[4];
  if ((threadIdx.x & 63) == 0) sred[threadIdx.x >> 6] = ss;
  __syncthreads();
  float r = rsqrtf((sred[0] + sred[1] + sred[2] + sred[3]) * (1.f / DIM) + 1e-6f);
#pragma unroll
  for (int i = 0; i < DIM / 256; ++i) {
    int idx = threadIdx.x + i * 256;
    o[b * DIM + idx] = w[idx] * xr[idx] * r;
  }
}

// ---------------------------------------------------------------- GEMV core
// 64-thread block computes 4 rows x 16 batches. Lane = float4 K-offset, so W
// loads are fully coalesced (1KB/instr). Per-lane partials a[r*16+b]; a
// 6-step halving butterfly leaves lane j with the total for (r=j>>4, b=j&15).
template <int K4>
__device__ __forceinline__ float gemv64(const float* __restrict__ W,
                                        const float* __restrict__ X, int row0) {
  const int lane = threadIdx.x & 63;
  const float4* __restrict__ Wv = (const float4*)W;
  const float4* __restrict__ Xv = (const float4*)X;
  float a[64];
#pragma unroll
  for (int j = 0; j < 64; ++j) a[j] = 0.f;
#pragma unroll 2
  for (int it = 0; it < K4 / 64; ++it) {
    int k = it * 64 + lane;
    float4 w0 = Wv[(size_t)(row0 + 0) * K4 + k];
    float4 w1 = Wv[(size_t)(row0 + 1) * K4 + k];
    float4 w2 = Wv[(size_t)(row0 + 2) * K4 + k];
    float4 w3 = Wv[(size_t)(row0 + 3) * K4 + k];
#pragma unroll
    for (int b = 0; b < 16; ++b) {
      float4 xb = Xv[(size_t)b * K4 + k];
      a[0 * 16 + b] += dot4(w0, xb);
      a[1 * 16 + b] += dot4(w1, xb);
      a[2 * 16 + b] += dot4(w2, xb);
      a[3 * 16 + b] += dot4(w3, xb);
    }
  }
  // butterfly: at step s exchange the half of the payload belonging to partner
#pragma unroll
  for (int s = 0; s < 6; ++s) {
    const int m = 1 << s;
    const int mybit = (lane >> s) & 1;
#pragma unroll
    for (int i = 0; i < (64 >> (s + 1)); ++i) {
      float x0 = a[2 * i], x1 = a[2 * i + 1];
      float keep = mybit ? x1 : x0;
      float give = mybit ? x0 : x1;
      a[i] = keep + __shfl_xor(give, m, 64);
    }
  }
  return a[0];
}

// ---------------------------------------------------------------- QKV + RoPE
__global__ __launch_bounds__(64) void qkv_k(const float* __restrict__ xn,
    const float* __restrict__ wq, const float* __restrict__ wk,
    const float* __restrict__ wv, const float* __restrict__ fc,
    const float* __restrict__ fs, float* __restrict__ qo,
    float* __restrict__ ck, float* __restrict__ cv) {
  int row0 = blockIdx.x * 4;  // over [q 2048 | k 512 | v 512]
  const float* W;
  int lr, kind;
  if (row0 < DIM)            { W = wq; lr = row0;             kind = 0; }
  else if (row0 < DIM + 512) { W = wk; lr = row0 - DIM;       kind = 1; }
  else                       { W = wv; lr = row0 - DIM - 512; kind = 2; }
  float v = gemv64<512>(W, xn, lr);
  float pv = __shfl_xor(v, 16, 64);  // partner row within rope pair
  int lane = threadIdx.x & 63;
  int r = lane >> 4, b = lane & 15;
  int dl = (lr & 63) + r;                    // head-local dim
  int jp = ((lr & 63) + (r & 2)) >> 1;       // rope pair index
  float c = fc[jp], sn = fs[jp];
  float o = (r & 1) ? (pv * sn + v * c) : (v * c - pv * sn);
  const float QS = 0.125f * 1.44269504088896f;  // 1/sqrt(64) * log2(e)
  if (kind == 0) {
    qo[b * DIM + lr + r] = o * QS;
  } else {
    int kvh = lr >> 6;
    float* cp = (kind == 1 ? ck : cv) +
                (((size_t)b * MAXSEQ + TPOS) * NKVh + kvh) * HDIM + dl;
    *cp = o;
  }
}

// ---------------------------------------------------------------- attention (split-T)
// 256 threads = 4 waves; lane = t8*8 + d8 : 8 t-positions x 8 d-slices.
// Per-lane online softmax over its own t-chain (32 independent chains/wave).
__global__ __launch_bounds__(256) void attn_part_k(const float* __restrict__ q,
    const float* __restrict__ ck, const float* __restrict__ cv,
    float* __restrict__ pml, float* __restrict__ po) {
  int blk = blockIdx.x;
  int sp = blk & (NSPLIT - 1);
  int bk = blk / NSPLIT;  // b*8+kv
  int kv = bk & 7, b = bk >> 3;
  int w = threadIdx.x >> 6, lane = threadIdx.x & 63;
  int t8 = lane >> 3, d8 = lane & 7;

  float4 q4[GRP][2];
#pragma unroll
  for (int g = 0; g < GRP; ++g) {
    const float* qp = q + b * DIM + (kv * GRP + g) * HDIM + d8 * 8;
    q4[g][0] = *(const float4*)qp;
    q4[g][1] = *(const float4*)(qp + 4);
  }

  float m[GRP], l[GRP];
  float4 o0[GRP], o1[GRP];
#pragma unroll
  for (int g = 0; g < GRP; ++g) {
    m[g] = -1e30f; l[g] = 0.f;
    o0[g] = make_float4(0.f, 0.f, 0.f, 0.f);
    o1[g] = make_float4(0.f, 0.f, 0.f, 0.f);
  }
  const size_t bkoff = ((size_t)b * MAXSEQ * NKVh + kv) * HDIM + d8 * 8;
  const float* Kp = ck + bkoff;
  const float* Vp = cv + bkoff;
  int tbase = sp * CHUNK + w * 128 + t8;
#pragma unroll 2
  for (int it = 0; it < 16; ++it) {
    size_t toff = (size_t)(tbase + it * 8) * (NKVh * HDIM);
    float4 ka = *(const float4*)(Kp + toff);
    float4 kb = *(const float4*)(Kp + toff + 4);
    float s[GRP];
#pragma unroll
    for (int g = 0; g < GRP; ++g)
      s[g] = dot4(ka, q4[g][0]) + dot4(kb, q4[g][1]);
#pragma unroll
    for (int msk = 1; msk < 8; msk <<= 1)
#pragma unroll
      for (int g = 0; g < GRP; ++g) s[g] += __shfl_xor(s[g], msk, 64);
    float4 va = *(const float4*)(Vp + toff);
    float4 vb = *(const float4*)(Vp + toff + 4);
#pragma unroll
    for (int g = 0; g < GRP; ++g) {
      float mn = fmaxf(m[g], s[g]);
      float sc = exp2f(m[g] - mn);
      float p  = exp2f(s[g] - mn);
      l[g] = l[g] * sc + p;
      o0[g].x = o0[g].x * sc + p * va.x;
      o0[g].y = o0[g].y * sc + p * va.y;
      o0[g].z = o0[g].z * sc + p * va.z;
      o0[g].w = o0[g].w * sc + p * va.w;
      o1[g].x = o1[g].x * sc + p * vb.x;
      o1[g].y = o1[g].y * sc + p * vb.y;
      o1[g].z = o1[g].z * sc + p * vb.z;
      o1[g].w = o1[g].w * sc + p * vb.w;
      m[g] = mn;
    }
  }
  // 32 partial sets (4 waves x 8 t8), each distributed over 8 d8 lanes
  __shared__ float sml[32][GRP][2];
  __shared__ float so[32][GRP][HDIM];
  int set = w * 8 + t8;
#pragma unroll
  for (int g = 0; g < GRP; ++g) {
    *(float4*)&so[set][g][d8 * 8]     = o0[g];
    *(float4*)&so[set][g][d8 * 8 + 4] = o1[g];
    if (d8 == 0) { sml[set][g][0] = m[g]; sml[set][g][1] = l[g]; }
  }
  __syncthreads();
  // combine 32 sets; thread owns (g, d)
  int g = threadIdx.x >> 6, d = threadIdx.x & 63;
  float M = -1e30f;
#pragma unroll
  for (int s2 = 0; s2 < 32; ++s2) M = fmaxf(M, sml[s2][g][0]);
  float L = 0.f, O = 0.f;
#pragma unroll
  for (int s2 = 0; s2 < 32; ++s2) {
    float e = exp2f(sml[s2][g][0] - M);
    L += e * sml[s2][g][1];
    O += e * so[s2][g][d];
  }
  int idx = (bk * GRP + g) * NSPLIT + sp;
  po[idx * HDIM + d] = O;
  if (d == 0) { pml[idx * 2] = M; pml[idx * 2 + 1] = L; }
}

__global__ __launch_bounds__(256) void attn_comb_k(const float* __restrict__ pml,
    const float* __restrict__ po, float* __restrict__ attn) {
  int t = blockIdx.x * 256 + threadIdx.x;  // 0..32767
  int d = t & 63, bkg = t >> 6;            // bkg = (b*8+kv)*4+g
  float M = -1e30f;
#pragma unroll
  for (int sp = 0; sp < NSPLIT; ++sp) M = fmaxf(M, pml[(bkg * NSPLIT + sp) * 2]);
  float L = 0.f, O = 0.f;
#pragma unroll
  for (int sp = 0; sp < NSPLIT; ++sp) {
    float e = exp2f(pml[(bkg * NSPLIT + sp) * 2] - M);
    L += e * pml[(bkg * NSPLIT + sp) * 2 + 1];
    O += e * po[(bkg * NSPLIT + sp) * HDIM + d];
  }
  attn[bkg * HDIM + d] = O / L;  // == b*2048 + (kv*4+g)*64 + d
}

// ---------------------------------------------------------------- wo + residual
__global__ __launch_bounds__(64) void wo_k(const float* __restrict__ attn,
    const float* __restrict__ wo, const float* __restrict__ x,
    float* __restrict__ h) {
  int row0 = blockIdx.x * 4;
  float v = gemv64<512>(wo, attn, row0);
  int lane = threadIdx.x & 63;
  int r = lane >> 4, b = lane & 15;
  h[b * DIM + row0 + r] = x[b * DIM + row0 + r] + v;
}

// ---------------------------------------------------------------- w1(silu) & w3
__global__ __launch_bounds__(64) void ffn13_k(const float* __restrict__ hn,
    const float* __restrict__ w1, const float* __restrict__ w3,
    float* __restrict__ h1, float* __restrict__ h3) {
  int row0 = blockIdx.x * 4;
  bool is1 = row0 < FFH;
  const float* W = is1 ? w1 : w3;
  int lr = is1 ? row0 : row0 - FFH;
  float v = gemv64<512>(W, hn, lr);
  int lane = threadIdx.x & 63;
  int r = lane >> 4, b = lane & 15;
  if (is1) h1[b * FFH + lr + r] = v / (1.f + expf(-v));
  else     h3[b * DIM + lr + r] = v;
}

// ---------------------------------------------------------------- w2 + residuals
__global__ __launch_bounds__(64) void ffn2_k(const float* __restrict__ h1,
    const float* __restrict__ w2, const float* __restrict__ h,
    const float* __restrict__ h3, float* __restrict__ out) {
  int row0 = blockIdx.x * 4;
  float v = gemv64<1408>(w2, h1, row0);
  int lane = threadIdx.x & 63;
  int r = lane >> 4, b = lane & 15;
  out[b * DIM + row0 + r] = h[b * DIM + row0 + r] + h3[b * DIM + row0 + r] + v;
}

// ---------------------------------------------------------------- launch
extern "C" void kernel_launch(void* const* d_in, const int* in_sizes, int n_in,
                              void* d_out, int out_size, void* d_ws, size_t ws_size,
                              hipStream_t stream) {
  (void)in_sizes; (void)n_in; (void)out_size; (void)ws_size;
  const float* x   = (const float*)d_in[0];
  const float* fc  = (const float*)d_in[1];
  const float* fs  = (const float*)d_in[2];
  float*       ck  = (float*)d_in[3];
  float*       cv  = (float*)d_in[4];
  const float* wq  = (const float*)d_in[5];
  const float* wk  = (const float*)d_in[6];
  const float* wvp = (const float*)d_in[7];
  const float* wo  = (const float*)d_in[8];
  const float* w1  = (const float*)d_in[9];
  const float* w2  = (const float*)d_in[10];
  const float* w3  = (const float*)d_in[11];
  const float* anw = (const float*)d_in[12];
  const float* fnw = (const float*)d_in[13];
  float* ws  = (float*)d_ws;
  float* out = (float*)d_out;

  rmsnorm_k<<<NB, 256, 0, stream>>>(x, anw, ws + XN_OFF);
  qkv_k<<<(DIM + 512 + 512) / 4, 64, 0, stream>>>(ws + XN_OFF, wq, wk, wvp, fc, fs,
                                                  ws + Q_OFF, ck, cv);
  attn_part_k<<<NB * NKVh * NSPLIT, 256, 0, stream>>>(ws + Q_OFF, ck, cv,
                                                      ws + PML_OFF, ws + PO_OFF);
  attn_comb_k<<<(NB * DIM) / 256, 256, 0, stream>>>(ws + PML_OFF, ws + PO_OFF, ws + ATTN_OFF);
  wo_k<<<DIM / 4, 64, 0, stream>>>(ws + ATTN_OFF, wo, x, ws + H_OFF);
  rmsnorm_k<<<NB, 256, 0, stream>>>(ws + H_OFF, fnw, ws + HN_OFF);
  ffn13_k<<<(FFH + DIM) / 4, 64, 0, stream>>>(ws + HN_OFF, w1, w3, ws + H1_OFF, ws + H3_OFF);
  ffn2_k<<<DIM / 4, 64, 0, stream>>>(ws + H1_OFF, w2, ws + H_OFF, ws + H3_OFF, out);
}

// Round 4
// 524.678 us; speedup vs baseline: 1.0010x; 1.0010x over previous
//
#include <hip/hip_runtime.h>
#include <math.h>

#define NB      16
#define DIM     2048
#define NKVh    8
#define HDIM    64
#define GRP     4
#define MAXSEQ  4096
#define TPOS    4095
#define FFH     5632
#define NSPLIT  4
#define CHUNK   1024

// workspace offsets (floats)
#define XN_OFF   0          // 16*2048
#define Q_OFF    32768      // 16*2048 (pre-scaled, roped q)
#define ATTN_OFF 65536      // 16*2048
#define H_OFF    98304      // 16*2048
#define HN_OFF   131072     // 16*2048
#define H1_OFF   163840     // 16*5632
#define H3_OFF   253952     // 16*2048
#define PML_OFF  286720
#define PO_OFF   294912

__device__ __forceinline__ float dot4(float4 a, float4 b) {
  return a.x * b.x + a.y * b.y + a.z * b.z + a.w * b.w;
}

#define GLOAD_LDS(srcp, ldsp)                                                  \
  __builtin_amdgcn_global_load_lds(                                            \
      (const __attribute__((address_space(1))) void*)(srcp),                   \
      (__attribute__((address_space(3))) void*)(ldsp), 16, 0, 0)

#define WAITBAR(N) asm volatile("s_waitcnt vmcnt(" #N ")\n\ts_barrier" ::: "memory")
#define RAWBAR()   asm volatile("s_barrier" ::: "memory")

// ---------------------------------------------------------------- RMSNorm
__global__ __launch_bounds__(256) void rmsnorm_k(const float* __restrict__ x,
    const float* __restrict__ w, float* __restrict__ o) {
  int b = blockIdx.x;
  const float* xr = x + b * DIM;
  float ss = 0.f;
#pragma unroll
  for (int i = 0; i < DIM / 256; ++i) {
    float v = xr[threadIdx.x + i * 256];
    ss += v * v;
  }
#pragma unroll
  for (int m = 32; m >= 1; m >>= 1) ss += __shfl_xor(ss, m, 64);
  __shared__ float sred[4];
  if ((threadIdx.x & 63) == 0) sred[threadIdx.x >> 6] = ss;
  __syncthreads();
  float r = rsqrtf((sred[0] + sred[1] + sred[2] + sred[3]) * (1.f / DIM) + 1e-6f);
#pragma unroll
  for (int i = 0; i < DIM / 256; ++i) {
    int idx = threadIdx.x + i * 256;
    o[b * DIM + idx] = w[idx] * xr[idx] * r;
  }
}

// ---------------------------------------------------------------- GEMV core
// 4-wave block, 16 rows (4 per wave) x 16 batches. W loads double-buffered
// (HBM stream); X loads clustered per iteration (L2-resident). Butterfly
// reduce leaves lane j holding total for (r=j>>4, b=j&15).
template <int K4>
__device__ __forceinline__ float gemv16(const float* __restrict__ W,
                                        const float* __restrict__ X,
                                        int row0) {
  constexpr int NIT = K4 / 64;
  const int lane = threadIdx.x & 63;
  const float4* __restrict__ Wv = (const float4*)W;
  const float4* __restrict__ Xv = (const float4*)X;
  float a[64];
#pragma unroll
  for (int j = 0; j < 64; ++j) a[j] = 0.f;
  float4 wa[4], wb[4];
#define LDW(dst, it) { int kk = (it) * 64 + lane;                              \
  _Pragma("unroll") for (int r = 0; r < 4; ++r)                                \
    dst[r] = Wv[(size_t)(row0 + r) * K4 + kk]; }
#define GST(wreg, it) { int kk = (it) * 64 + lane; float4 xx[16];              \
  _Pragma("unroll") for (int bb = 0; bb < 16; ++bb)                            \
    xx[bb] = Xv[(size_t)bb * K4 + kk];                                         \
  _Pragma("unroll") for (int bb = 0; bb < 16; ++bb) {                          \
    a[0 * 16 + bb] += dot4(wreg[0], xx[bb]);                                   \
    a[1 * 16 + bb] += dot4(wreg[1], xx[bb]);                                   \
    a[2 * 16 + bb] += dot4(wreg[2], xx[bb]);                                   \
    a[3 * 16 + bb] += dot4(wreg[3], xx[bb]); } }
  LDW(wa, 0);
#pragma unroll 1
  for (int it = 0; it < NIT - 2; it += 2) {
    LDW(wb, it + 1);
    GST(wa, it);
    LDW(wa, it + 2);
    GST(wb, it + 1);
  }
  LDW(wb, NIT - 1);
  GST(wa, NIT - 2);
  GST(wb, NIT - 1);
#undef LDW
#undef GST
  // butterfly: at step s exchange the half of the payload belonging to partner
#pragma unroll
  for (int s = 0; s < 6; ++s) {
    const int m = 1 << s;
    const int mybit = (lane >> s) & 1;
#pragma unroll
    for (int i = 0; i < (64 >> (s + 1)); ++i) {
      float x0 = a[2 * i], x1 = a[2 * i + 1];
      float keep = mybit ? x1 : x0;
      float give = mybit ? x0 : x1;
      a[i] = keep + __shfl_xor(give, m, 64);
    }
  }
  return a[0];
}

// ---------------------------------------------------------------- QKV + RoPE
__global__ __launch_bounds__(256, 2) void qkv_k(const float* __restrict__ xn,
    const float* __restrict__ wq, const float* __restrict__ wk,
    const float* __restrict__ wv, const float* __restrict__ fc,
    const float* __restrict__ fs, float* __restrict__ qo,
    float* __restrict__ ck, float* __restrict__ cv) {
  int rb = blockIdx.x * 16;  // over [q 2048 | k 512 | v 512]
  const float* W;
  int lrb, kind;
  if (rb < DIM)            { W = wq; lrb = rb;             kind = 0; }
  else if (rb < DIM + 512) { W = wk; lrb = rb - DIM;       kind = 1; }
  else                     { W = wv; lrb = rb - DIM - 512; kind = 2; }
  int wv_ = threadIdx.x >> 6;
  int lr = lrb + wv_ * 4;
  float v = gemv16<512>(W, xn, lr);
  float pv = __shfl_xor(v, 16, 64);  // partner row within rope pair
  int lane = threadIdx.x & 63;
  int r = lane >> 4, b = lane & 15;
  int dl = (lr & 63) + r;                    // head-local dim
  int jp = ((lr & 63) + (r & 2)) >> 1;       // rope pair index
  float c = fc[jp], sn = fs[jp];
  float o = (r & 1) ? (pv * sn + v * c) : (v * c - pv * sn);
  const float QS = 0.125f * 1.44269504088896f;  // 1/sqrt(64) * log2(e)
  if (kind == 0) {
    qo[b * DIM + lr + r] = o * QS;
  } else {
    int kvh = lr >> 6;
    float* cp = (kind == 1 ? ck : cv) +
                (((size_t)b * MAXSEQ + TPOS) * NKVh + kvh) * HDIM + dl;
    *cp = o;
  }
}

// ---------------------------------------------------------------- attention (split-T)
// 256 threads = 4 waves; lane = t8*8 + d8. K/V staged in LDS via
// global_load_lds (dense 1KB/instr), 4 buffers, depth-2 prefetch with counted
// vmcnt (never 0 in loop). LDS chunk index XOR-swizzled (c ^ t8) against the
// 16-way b128 bank conflict; source addresses carry the inverse swizzle.
__global__ __launch_bounds__(256) void attn_part_k(const float* __restrict__ q,
    const float* __restrict__ ck, const float* __restrict__ cv,
    float* __restrict__ pml, float* __restrict__ po) {
  __shared__ float smem[16384];  // 4 buffers x (K 2048 | V 2048) floats
  int blk = blockIdx.x;
  int sp = blk & (NSPLIT - 1);
  int bk = blk >> 2;  // b*8+kv
  int kv = bk & 7, b = bk >> 3;
  int tid = threadIdx.x;
  int w = tid >> 6, lane = tid & 63;
  int t8 = lane >> 3, d8 = lane & 7;
  int c0 = (d8 * 2) ^ t8, c1 = c0 ^ 1;
  const int r4 = lane >> 4;   // staging: row within quad
  const int cps = lane & 15;  // staging: phys chunk slot

  const size_t kvbase = ((size_t)b * MAXSEQ * NKVh + kv) * HDIM;
  const float* Kpl = ck + kvbase;
  const float* Vpl = cv + kvbase;

  float4 q40[GRP], q41[GRP];
#pragma unroll
  for (int g = 0; g < GRP; ++g) {
    const float* qp = q + b * DIM + (kv * GRP + g) * HDIM + d8 * 8;
    q40[g] = *(const float4*)qp;
    q41[g] = *(const float4*)(qp + 4);
  }
  float m[GRP], l[GRP];
  float4 o0[GRP], o1[GRP];
#pragma unroll
  for (int g = 0; g < GRP; ++g) {
    m[g] = -1e30f; l[g] = 0.f;
    o0[g] = make_float4(0.f, 0.f, 0.f, 0.f);
    o1[g] = make_float4(0.f, 0.f, 0.f, 0.f);
  }
  const int tg0 = sp * CHUNK;
  const int sw0 = (cps ^ r4) * 4;        // inverse-swizzled float offset, rows r4
  const int sw1 = (cps ^ (4 + r4)) * 4;  // rows 4+r4

#define STAGE(tile, bi) {                                                      \
    int tbase = tg0 + (tile) * 32 + w * 8;                                     \
    const float* Ks = Kpl + (size_t)tbase * (NKVh * HDIM);                     \
    const float* Vs = Vpl + (size_t)tbase * (NKVh * HDIM);                     \
    float* dK = smem + (bi) * 4096 + (w * 8) * 64;                             \
    float* dV = dK + 2048;                                                     \
    GLOAD_LDS(Ks + (size_t)r4 * 512 + sw0, dK);                                \
    GLOAD_LDS(Ks + (size_t)(4 + r4) * 512 + sw1, dK + 256);                    \
    GLOAD_LDS(Vs + (size_t)r4 * 512 + sw0, dV);                                \
    GLOAD_LDS(Vs + (size_t)(4 + r4) * 512 + sw1, dV + 256); }

#define COMPUTE(bi) {                                                          \
    const float4* bK = (const float4*)(smem + (bi) * 4096);                    \
    const float4* bV = bK + 512;                                               \
    int base = (w * 8 + t8) * 16;                                              \
    float4 ka = bK[base + c0], kb = bK[base + c1];                             \
    float4 va = bV[base + c0], vb = bV[base + c1];                             \
    float s_[GRP];                                                             \
    _Pragma("unroll") for (int g = 0; g < GRP; ++g)                            \
      s_[g] = dot4(ka, q40[g]) + dot4(kb, q41[g]);                             \
    _Pragma("unroll") for (int msk = 1; msk < 8; msk <<= 1)                    \
      _Pragma("unroll") for (int g = 0; g < GRP; ++g)                          \
        s_[g] += __shfl_xor(s_[g], msk, 64);                                   \
    _Pragma("unroll") for (int g = 0; g < GRP; ++g) {                          \
      float mn = fmaxf(m[g], s_[g]);                                           \
      float sc = exp2f(m[g] - mn);                                             \
      float p  = exp2f(s_[g] - mn);                                            \
      l[g] = l[g] * sc + p;                                                    \
      o0[g].x = o0[g].x * sc + p * va.x;                                       \
      o0[g].y = o0[g].y * sc + p * va.y;                                       \
      o0[g].z = o0[g].z * sc + p * va.z;                                       \
      o0[g].w = o0[g].w * sc + p * va.w;                                       \
      o1[g].x = o1[g].x * sc + p * vb.x;                                       \
      o1[g].y = o1[g].y * sc + p * vb.y;                                       \
      o1[g].z = o1[g].z * sc + p * vb.z;                                       \
      o1[g].w = o1[g].w * sc + p * vb.w;                                       \
      m[g] = mn; } }

#define STEPF(ti, bi, sbi) { STAGE((ti) + 2, sbi); WAITBAR(8); COMPUTE(bi); RAWBAR(); }

  STAGE(0, 0);
  STAGE(1, 1);
#pragma unroll 1
  for (int t = 0; t < 28; t += 4) {
    STEPF(t + 0, 0, 2);
    STEPF(t + 1, 1, 3);
    STEPF(t + 2, 2, 0);
    STEPF(t + 3, 3, 1);
  }
  STEPF(28, 0, 2);                       // stages tile 30
  STEPF(29, 1, 3);                       // stages tile 31
  { WAITBAR(4); COMPUTE(2); RAWBAR(); }  // tile 30
  { WAITBAR(0); COMPUTE(3); }            // tile 31
#undef STAGE
#undef COMPUTE
#undef STEPF

  __syncthreads();
  float* so  = smem;         // [32][GRP][64]
  float* sml = smem + 8192;  // [32][GRP][2]
  int set = w * 8 + t8;
#pragma unroll
  for (int g = 0; g < GRP; ++g) {
    *(float4*)&so[(set * GRP + g) * 64 + d8 * 8]     = o0[g];
    *(float4*)&so[(set * GRP + g) * 64 + d8 * 8 + 4] = o1[g];
    if (d8 == 0) { sml[(set * GRP + g) * 2] = m[g]; sml[(set * GRP + g) * 2 + 1] = l[g]; }
  }
  __syncthreads();
  int g2 = tid >> 6, d = tid & 63;
  float M = -1e30f;
#pragma unroll
  for (int s2 = 0; s2 < 32; ++s2) M = fmaxf(M, sml[(s2 * GRP + g2) * 2]);
  float L = 0.f, O = 0.f;
#pragma unroll
  for (int s2 = 0; s2 < 32; ++s2) {
    float e = exp2f(sml[(s2 * GRP + g2) * 2] - M);
    L += e * sml[(s2 * GRP + g2) * 2 + 1];
    O += e * so[(s2 * GRP + g2) * 64 + d];
  }
  int idx = (bk * GRP + g2) * NSPLIT + sp;
  po[idx * HDIM + d] = O;
  if (d == 0) { pml[idx * 2] = M; pml[idx * 2 + 1] = L; }
}

__global__ __launch_bounds__(256) void attn_comb_k(const float* __restrict__ pml,
    const float* __restrict__ po, float* __restrict__ attn) {
  int t = blockIdx.x * 256 + threadIdx.x;  // 0..32767
  int d = t & 63, bkg = t >> 6;            // bkg = (b*8+kv)*4+g
  float M = -1e30f;
#pragma unroll
  for (int sp = 0; sp < NSPLIT; ++sp) M = fmaxf(M, pml[(bkg * NSPLIT + sp) * 2]);
  float L = 0.f, O = 0.f;
#pragma unroll
  for (int sp = 0; sp < NSPLIT; ++sp) {
    float e = exp2f(pml[(bkg * NSPLIT + sp) * 2] - M);
    L += e * pml[(bkg * NSPLIT + sp) * 2 + 1];
    O += e * po[(bkg * NSPLIT + sp) * HDIM + d];
  }
  attn[bkg * HDIM + d] = O / L;  // == b*2048 + (kv*4+g)*64 + d
}

// ---------------------------------------------------------------- wo + residual
__global__ __launch_bounds__(256, 2) void wo_k(const float* __restrict__ attn,
    const float* __restrict__ wo, const float* __restrict__ x,
    float* __restrict__ h) {
  int row0 = blockIdx.x * 16 + (threadIdx.x >> 6) * 4;
  float v = gemv16<512>(wo, attn, row0);
  int lane = threadIdx.x & 63;
  int r = lane >> 4, b = lane & 15;
  h[b * DIM + row0 + r] = x[b * DIM + row0 + r] + v;
}

// ---------------------------------------------------------------- w1(silu) & w3
__global__ __launch_bounds__(256, 2) void ffn13_k(const float* __restrict__ hn,
    const float* __restrict__ w1, const float* __restrict__ w3,
    float* __restrict__ h1, float* __restrict__ h3) {
  int rb = blockIdx.x * 16;
  bool is1 = rb < FFH;
  const float* W = is1 ? w1 : w3;
  int lr = (is1 ? rb : rb - FFH) + (threadIdx.x >> 6) * 4;
  float v = gemv16<512>(W, hn, lr);
  int lane = threadIdx.x & 63;
  int r = lane >> 4, b = lane & 15;
  if (is1) h1[b * FFH + lr + r] = v / (1.f + expf(-v));
  else     h3[b * DIM + lr + r] = v;
}

// ---------------------------------------------------------------- w2 + residuals
__global__ __launch_bounds__(256, 2) void ffn2_k(const float* __restrict__ h1,
    const float* __restrict__ w2, const float* __restrict__ h,
    const float* __restrict__ h3, float* __restrict__ out) {
  int row0 = blockIdx.x * 16 + (threadIdx.x >> 6) * 4;
  float v = gemv16<1408>(w2, h1, row0);
  int lane = threadIdx.x & 63;
  int r = lane >> 4, b = lane & 15;
  out[b * DIM + row0 + r] = h[b * DIM + row0 + r] + h3[b * DIM + row0 + r] + v;
}

// ---------------------------------------------------------------- launch
extern "C" void kernel_launch(void* const* d_in, const int* in_sizes, int n_in,
                              void* d_out, int out_size, void* d_ws, size_t ws_size,
                              hipStream_t stream) {
  (void)in_sizes; (void)n_in; (void)out_size; (void)ws_size;
  const float* x   = (const float*)d_in[0];
  const float* fc  = (const float*)d_in[1];
  const float* fs  = (const float*)d_in[2];
  float*       ck  = (float*)d_in[3];
  float*       cv  = (float*)d_in[4];
  const float* wq  = (const float*)d_in[5];
  const float* wk  = (const float*)d_in[6];
  const float* wvp = (const float*)d_in[7];
  const float* wo  = (const float*)d_in[8];
  const float* w1  = (const float*)d_in[9];
  const float* w2  = (const float*)d_in[10];
  const float* w3  = (const float*)d_in[11];
  const float* anw = (const float*)d_in[12];
  const float* fnw = (const float*)d_in[13];
  float* ws  = (float*)d_ws;
  float* out = (float*)d_out;

  rmsnorm_k<<<NB, 256, 0, stream>>>(x, anw, ws + XN_OFF);
  qkv_k<<<(DIM + 512 + 512) / 16, 256, 0, stream>>>(ws + XN_OFF, wq, wk, wvp, fc, fs,
                                                    ws + Q_OFF, ck, cv);
  attn_part_k<<<NB * NKVh * NSPLIT, 256, 0, stream>>>(ws + Q_OFF, ck, cv,
                                                      ws + PML_OFF, ws + PO_OFF);
  attn_comb_k<<<(NB * DIM) / 256, 256, 0, stream>>>(ws + PML_OFF, ws + PO_OFF, ws + ATTN_OFF);
  wo_k<<<DIM / 16, 256, 0, stream>>>(ws + ATTN_OFF, wo, x, ws + H_OFF);
  rmsnorm_k<<<NB, 256, 0, stream>>>(ws + H_OFF, fnw, ws + HN_OFF);
  ffn13_k<<<(FFH + DIM) / 16, 256, 0, stream>>>(ws + HN_OFF, w1, w3, ws + H1_OFF, ws + H3_OFF);
  ffn2_k<<<DIM / 16, 256, 0, stream>>>(ws + H1_OFF, w2, ws + H_OFF, ws + H3_OFF, out);
}

// Round 8
// 467.679 us; speedup vs baseline: 1.1230x; 1.1219x over previous
//
#include <hip/hip_runtime.h>
#include <math.h>

#define NB      16
#define DIM     2048
#define NKVh    8
#define HDIM    64
#define GRP     4
#define MAXSEQ  4096
#define TPOS    4095
#define FFH     5632
#define NSPLIT  16
#define TSPAN   256   // t-range per attn block
#define TROW    512   // floats per t row (NKVh*HDIM)

// workspace offsets (floats)
#define XN_OFF   0          // 16*2048
#define Q_OFF    32768      // 16*2048 (pre-scaled, roped q)
#define ATTN_OFF 65536      // 16*2048
#define H_OFF    98304      // 16*2048
#define HN_OFF   131072     // 16*2048
#define H1_OFF   163840     // 16*5632
#define H3_OFF   253952     // 16*2048
#define PML_OFF  286720     // 16*8*4*16*2 = 16384
#define PO_OFF   303104     // 16*8*4*16*64 = 524288

__device__ __forceinline__ float dot4(float4 a, float4 b) {
  return a.x * b.x + a.y * b.y + a.z * b.z + a.w * b.w;
}

#define GLOAD_LDS(srcp, ldsp)                                                  \
  __builtin_amdgcn_global_load_lds(                                            \
      (const __attribute__((address_space(1))) void*)(srcp),                   \
      (__attribute__((address_space(3))) void*)(ldsp), 16, 0, 0)

#define WAITBAR(N) asm volatile("s_waitcnt vmcnt(" #N ")\n\ts_barrier" ::: "memory")

// ---------------------------------------------------------------- RMSNorm
__global__ __launch_bounds__(256) void rmsnorm_k(const float* __restrict__ x,
    const float* __restrict__ w, float* __restrict__ o) {
  int b = blockIdx.x;
  const float* xr = x + b * DIM;
  float ss = 0.f;
#pragma unroll
  for (int i = 0; i < DIM / 256; ++i) {
    float v = xr[threadIdx.x + i * 256];
    ss += v * v;
  }
#pragma unroll
  for (int m = 32; m >= 1; m >>= 1) ss += __shfl_xor(ss, m, 64);
  __shared__ float sred[4];
  if ((threadIdx.x & 63) == 0) sred[threadIdx.x >> 6] = ss;
  __syncthreads();
  float r = rsqrtf((sred[0] + sred[1] + sred[2] + sred[3]) * (1.f / DIM) + 1e-6f);
#pragma unroll
  for (int i = 0; i < DIM / 256; ++i) {
    int idx = threadIdx.x + i * 256;
    o[b * DIM + idx] = w[idx] * xr[idx] * r;
  }
}

// ---------------------------------------------------------------- GEMV core
// 128-thread block (2 waves, K halves). lane = b4*16+lk. Computes 4 rows x 16
// batches. Ping-pong prefetch: next iteration's 8 loads (4 W rows + 4 X
// groups) issue before the current FMA block consumes its registers.
template <int K4>
__device__ __forceinline__ void gemv_core(const float* __restrict__ W,
                                          const float* __restrict__ X,
                                          int row0, float acc[4][4]) {
  const int lane = threadIdx.x & 63;
  const int wv   = threadIdx.x >> 6;
  const int lk   = lane & 15;
  const int b4   = lane >> 4;
  const float4* __restrict__ Wv = (const float4*)W;
  const float4* __restrict__ Xv = (const float4*)X;
#pragma unroll
  for (int r = 0; r < 4; ++r)
#pragma unroll
    for (int j = 0; j < 4; ++j) acc[r][j] = 0.f;
  constexpr int NI = K4 / 32;  // per-wave 16-wide float4 iterations (K4/2/16)
  const int k0 = wv * (K4 / 2) + lk;
  float4 aw0, aw1, aw2, aw3, ax0, ax1, ax2, ax3;
  float4 bw0, bw1, bw2, bw3, bx0, bx1, bx2, bx3;
#define LDA(S, it) { int kk = k0 + (it) * 16;                                  \
    S##w0 = Wv[(size_t)(row0 + 0) * K4 + kk];                                  \
    S##w1 = Wv[(size_t)(row0 + 1) * K4 + kk];                                  \
    S##w2 = Wv[(size_t)(row0 + 2) * K4 + kk];                                  \
    S##w3 = Wv[(size_t)(row0 + 3) * K4 + kk];                                  \
    S##x0 = Xv[(size_t)(b4 + 0) * K4 + kk];                                    \
    S##x1 = Xv[(size_t)(b4 + 4) * K4 + kk];                                    \
    S##x2 = Xv[(size_t)(b4 + 8) * K4 + kk];                                    \
    S##x3 = Xv[(size_t)(b4 + 12) * K4 + kk]; }
#define FMA4(S) {                                                              \
    acc[0][0] += dot4(S##w0, S##x0); acc[0][1] += dot4(S##w0, S##x1);          \
    acc[0][2] += dot4(S##w0, S##x2); acc[0][3] += dot4(S##w0, S##x3);          \
    acc[1][0] += dot4(S##w1, S##x0); acc[1][1] += dot4(S##w1, S##x1);          \
    acc[1][2] += dot4(S##w1, S##x2); acc[1][3] += dot4(S##w1, S##x3);          \
    acc[2][0] += dot4(S##w2, S##x0); acc[2][1] += dot4(S##w2, S##x1);          \
    acc[2][2] += dot4(S##w2, S##x2); acc[2][3] += dot4(S##w2, S##x3);          \
    acc[3][0] += dot4(S##w3, S##x0); acc[3][1] += dot4(S##w3, S##x1);          \
    acc[3][2] += dot4(S##w3, S##x2); acc[3][3] += dot4(S##w3, S##x3); }
  LDA(a, 0);
#pragma unroll 1
  for (int it = 0; it + 2 < NI; it += 2) {
    LDA(b, it + 1);
    FMA4(a);
    LDA(a, it + 2);
    FMA4(b);
  }
  LDA(b, NI - 1);
  FMA4(a);
  FMA4(b);
#undef LDA
#undef FMA4
  // reduce across the 16 k-lanes
#pragma unroll
  for (int m = 1; m < 16; m <<= 1)
#pragma unroll
    for (int r = 0; r < 4; ++r)
#pragma unroll
      for (int j = 0; j < 4; ++j) acc[r][j] += __shfl_xor(acc[r][j], m, 64);
  // combine the two waves via LDS
  __shared__ float sred[4][4][4];  // [b4][r][j]
  if (wv == 1 && lk == 0) {
#pragma unroll
    for (int r = 0; r < 4; ++r)
#pragma unroll
      for (int j = 0; j < 4; ++j) sred[b4][r][j] = acc[r][j];
  }
  __syncthreads();
  if (wv == 0) {
#pragma unroll
    for (int r = 0; r < 4; ++r)
#pragma unroll
      for (int j = 0; j < 4; ++j) acc[r][j] += sred[b4][r][j];
  }
}

// ---------------------------------------------------------------- QKV + RoPE
__global__ __launch_bounds__(128) void qkv_k(const float* __restrict__ xn,
    const float* __restrict__ wq, const float* __restrict__ wk,
    const float* __restrict__ wv, const float* __restrict__ fc,
    const float* __restrict__ fs, float* __restrict__ qo,
    float* __restrict__ ck, float* __restrict__ cv) {
  int row0 = blockIdx.x * 4;  // over [q 2048 | k 512 | v 512]
  const float* W;
  int lr, kind;
  if (row0 < DIM)            { W = wq; lr = row0;             kind = 0; }
  else if (row0 < DIM + 512) { W = wk; lr = row0 - DIM;       kind = 1; }
  else                       { W = wv; lr = row0 - DIM - 512; kind = 2; }
  float acc[4][4];
  gemv_core<512>(W, xn, lr, acc);
  if ((threadIdx.x >> 6) != 0 || (threadIdx.x & 15) != 0) return;
  int b4 = (threadIdx.x >> 4) & 3;
  int dl = lr & 63;      // head-local dim of row lr (multiple of 4)
  int j0 = dl >> 1;
  float c0 = fc[j0], s0 = fs[j0], c1 = fc[j0 + 1], s1 = fs[j0 + 1];
  const float QS = 0.125f * 1.44269504088896f;  // 1/sqrt(64) * log2(e)
#pragma unroll
  for (int j = 0; j < 4; ++j) {
    int b = b4 + 4 * j;
    float a0 = acc[0][j], a1 = acc[1][j], a2 = acc[2][j], a3 = acc[3][j];
    float o0 = a0 * c0 - a1 * s0, o1 = a0 * s0 + a1 * c0;
    float o2 = a2 * c1 - a3 * s1, o3 = a2 * s1 + a3 * c1;
    if (kind == 0) {
      float* qp = qo + b * DIM + lr;
      qp[0] = o0 * QS; qp[1] = o1 * QS; qp[2] = o2 * QS; qp[3] = o3 * QS;
    } else {
      int kvh = lr >> 6;
      float* cp = (kind == 1 ? ck : cv) +
                  (((size_t)b * MAXSEQ + TPOS) * NKVh + kvh) * HDIM + dl;
      cp[0] = o0; cp[1] = o1; cp[2] = o2; cp[3] = o3;
    }
  }
}

// ---------------------------------------------------------------- attention
// Block = (b, sp): 512 threads = 8 waves, wave w = kv head w. Staging reads
// cache[b][t][*][*] rows CONTIGUOUSLY (2 KB per row, waves 0-3 stage K rows,
// 4-7 stage V rows) into 4 x 16 KB LDS buffers; depth-2 prefetch, one counted
// vmcnt(4)+barrier per 4-t tile. Compute: lane = t4*16+dl; per-lane online
// softmax; LDS reads contiguous per 16-lane quarter (conflict-free).
__global__ __launch_bounds__(512) void attn_part_k(const float* __restrict__ q,
    const float* __restrict__ ck, const float* __restrict__ cv,
    float* __restrict__ pml, float* __restrict__ po) {
  __shared__ float smem[16384];  // 64 KB: 4 bufs x (K 4x512 | V 4x512)
  int sp = blockIdx.x & (NSPLIT - 1);
  int b  = blockIdx.x >> 4;
  int tid = threadIdx.x;
  int w = tid >> 6, lane = tid & 63;
  int t4 = lane >> 4, dl = lane & 15;

  const float* Kg = ck + ((size_t)b * MAXSEQ + sp * TSPAN) * TROW;
  const float* Vg = cv + ((size_t)b * MAXSEQ + sp * TSPAN) * TROW;
  const float* Sg = (w < 4) ? Kg : Vg;   // staging role
  const int    srow = w & 3;             // staging row within tile

  float4 q4[GRP];
#pragma unroll
  for (int g = 0; g < GRP; ++g)
    q4[g] = *(const float4*)(q + b * DIM + (w * GRP + g) * HDIM + dl * 4);

  float m[GRP], l[GRP];
  float4 o[GRP];
#pragma unroll
  for (int g = 0; g < GRP; ++g) {
    m[g] = -1e30f; l[g] = 0.f;
    o[g] = make_float4(0.f, 0.f, 0.f, 0.f);
  }

#define STAGE(tile) {                                                          \
    const float* src = Sg + ((size_t)(tile) * 4 + srow) * TROW + lane * 4;     \
    float* dst = smem + (((tile) & 3) * 4096) + ((w >= 4) ? 2048 : 0) +        \
                 srow * TROW;                                                  \
    GLOAD_LDS(src, dst);                                                       \
    GLOAD_LDS(src + 256, dst + 256); }

#define COMPUTE(tile) {                                                        \
    const float* bb = smem + (((tile) & 3) * 4096) + t4 * TROW + w * 64 + dl * 4; \
    float4 ka = *(const float4*)bb;                                            \
    float4 va = *(const float4*)(bb + 2048);                                   \
    float s_[GRP];                                                             \
    _Pragma("unroll") for (int g = 0; g < GRP; ++g) s_[g] = dot4(ka, q4[g]);   \
    _Pragma("unroll") for (int msk = 1; msk < 16; msk <<= 1)                   \
      _Pragma("unroll") for (int g = 0; g < GRP; ++g)                          \
        s_[g] += __shfl_xor(s_[g], msk, 64);                                   \
    _Pragma("unroll") for (int g = 0; g < GRP; ++g) {                          \
      float mn = fmaxf(m[g], s_[g]);                                           \
      float sc = exp2f(m[g] - mn);                                             \
      float p  = exp2f(s_[g] - mn);                                            \
      l[g] = l[g] * sc + p;                                                    \
      o[g].x = o[g].x * sc + p * va.x;                                         \
      o[g].y = o[g].y * sc + p * va.y;                                         \
      o[g].z = o[g].z * sc + p * va.z;                                         \
      o[g].w = o[g].w * sc + p * va.w;                                         \
      m[g] = mn; } }

  STAGE(0);
  STAGE(1);
#pragma unroll 1
  for (int t = 0; t < 62; ++t) {
    STAGE(t + 2);
    WAITBAR(4);
    COMPUTE(t);
  }
  WAITBAR(2);
  COMPUTE(62);
  WAITBAR(0);
  COMPUTE(63);
#undef STAGE
#undef COMPUTE

  __syncthreads();
  // 4 partial sets per (kv, g) — one per t4 group; o distributed over 16 dl.
  float* so  = smem;         // [8 kv][4 t4][GRP][64]
  float* sml = smem + 8192;  // [8 kv][4 t4][GRP][2]
#pragma unroll
  for (int g = 0; g < GRP; ++g) {
    *(float4*)&so[(((w * 4 + t4) * GRP) + g) * 64 + dl * 4] = o[g];
    if (dl == 0) {
      sml[(((w * 4 + t4) * GRP) + g) * 2]     = m[g];
      sml[(((w * 4 + t4) * GRP) + g) * 2 + 1] = l[g];
    }
  }
  __syncthreads();
  int kv2 = tid >> 6, d = tid & 63;
#pragma unroll
  for (int g = 0; g < GRP; ++g) {
    float M = -1e30f;
#pragma unroll
    for (int s2 = 0; s2 < 4; ++s2)
      M = fmaxf(M, sml[(((kv2 * 4 + s2) * GRP) + g) * 2]);
    float L = 0.f, O = 0.f;
#pragma unroll
    for (int s2 = 0; s2 < 4; ++s2) {
      float e = exp2f(sml[(((kv2 * 4 + s2) * GRP) + g) * 2] - M);
      L += e * sml[(((kv2 * 4 + s2) * GRP) + g) * 2 + 1];
      O += e * so[(((kv2 * 4 + s2) * GRP) + g) * 64 + d];
    }
    int idx = ((b * NKVh + kv2) * GRP + g) * NSPLIT + sp;
    po[idx * HDIM + d] = O;
    if (d == 0) { pml[idx * 2] = M; pml[idx * 2 + 1] = L; }
  }
}

__global__ __launch_bounds__(256) void attn_comb_k(const float* __restrict__ pml,
    const float* __restrict__ po, float* __restrict__ attn) {
  int t = blockIdx.x * 256 + threadIdx.x;  // 0..32767
  int d = t & 63, bkg = t >> 6;            // bkg = (b*8+kv)*4+g
  float M = -1e30f;
#pragma unroll
  for (int sp = 0; sp < NSPLIT; ++sp) M = fmaxf(M, pml[(bkg * NSPLIT + sp) * 2]);
  float L = 0.f, O = 0.f;
#pragma unroll
  for (int sp = 0; sp < NSPLIT; ++sp) {
    float e = exp2f(pml[(bkg * NSPLIT + sp) * 2] - M);
    L += e * pml[(bkg * NSPLIT + sp) * 2 + 1];
    O += e * po[(bkg * NSPLIT + sp) * HDIM + d];
  }
  attn[bkg * HDIM + d] = O / L;  // == b*2048 + (kv*4+g)*64 + d
}

// ---------------------------------------------------------------- wo + residual
__global__ __launch_bounds__(128) void wo_k(const float* __restrict__ attn,
    const float* __restrict__ wo, const float* __restrict__ x,
    float* __restrict__ h) {
  int row0 = blockIdx.x * 4;
  float acc[4][4];
  gemv_core<512>(wo, attn, row0, acc);
  if ((threadIdx.x >> 6) != 0 || (threadIdx.x & 15) != 0) return;
  int b4 = (threadIdx.x >> 4) & 3;
#pragma unroll
  for (int j = 0; j < 4; ++j) {
    int b = b4 + 4 * j;
#pragma unroll
    for (int r = 0; r < 4; ++r)
      h[b * DIM + row0 + r] = x[b * DIM + row0 + r] + acc[r][j];
  }
}

// ---------------------------------------------------------------- w1(silu) & w3
__global__ __launch_bounds__(128) void ffn13_k(const float* __restrict__ hn,
    const float* __restrict__ w1, const float* __restrict__ w3,
    float* __restrict__ h1, float* __restrict__ h3) {
  int row0 = blockIdx.x * 4;
  bool is1 = row0 < FFH;
  const float* W = is1 ? w1 : w3;
  int lr = is1 ? row0 : row0 - FFH;
  float acc[4][4];
  gemv_core<512>(W, hn, lr, acc);
  if ((threadIdx.x >> 6) != 0 || (threadIdx.x & 15) != 0) return;
  int b4 = (threadIdx.x >> 4) & 3;
#pragma unroll
  for (int j = 0; j < 4; ++j) {
    int b = b4 + 4 * j;
#pragma unroll
    for (int r = 0; r < 4; ++r) {
      float v = acc[r][j];
      if (is1) h1[b * FFH + lr + r] = v / (1.f + expf(-v));
      else     h3[b * DIM + lr + r] = v;
    }
  }
}

// ---------------------------------------------------------------- w2 + residuals
__global__ __launch_bounds__(128) void ffn2_k(const float* __restrict__ h1,
    const float* __restrict__ w2, const float* __restrict__ h,
    const float* __restrict__ h3, float* __restrict__ out) {
  int row0 = blockIdx.x * 4;
  float acc[4][4];
  gemv_core<1408>(w2, h1, row0, acc);
  if ((threadIdx.x >> 6) != 0 || (threadIdx.x & 15) != 0) return;
  int b4 = (threadIdx.x >> 4) & 3;
#pragma unroll
  for (int j = 0; j < 4; ++j) {
    int b = b4 + 4 * j;
#pragma unroll
    for (int r = 0; r < 4; ++r)
      out[b * DIM + row0 + r] = h[b * DIM + row0 + r] + h3[b * DIM + row0 + r] + acc[r][j];
  }
}

// ---------------------------------------------------------------- launch
extern "C" void kernel_launch(void* const* d_in, const int* in_sizes, int n_in,
                              void* d_out, int out_size, void* d_ws, size_t ws_size,
                              hipStream_t stream) {
  (void)in_sizes; (void)n_in; (void)out_size; (void)ws_size;
  const float* x   = (const float*)d_in[0];
  const float* fc  = (const float*)d_in[1];
  const float* fs  = (const float*)d_in[2];
  float*       ck  = (float*)d_in[3];
  float*       cv  = (float*)d_in[4];
  const float* wq  = (const float*)d_in[5];
  const float* wk  = (const float*)d_in[6];
  const float* wvp = (const float*)d_in[7];
  const float* wo  = (const float*)d_in[8];
  const float* w1  = (const float*)d_in[9];
  const float* w2  = (const float*)d_in[10];
  const float* w3  = (const float*)d_in[11];
  const float* anw = (const float*)d_in[12];
  const float* fnw = (const float*)d_in[13];
  float* ws  = (float*)d_ws;
  float* out = (float*)d_out;

  rmsnorm_k<<<NB, 256, 0, stream>>>(x, anw, ws + XN_OFF);
  qkv_k<<<(DIM + 512 + 512) / 4, 128, 0, stream>>>(ws + XN_OFF, wq, wk, wvp, fc, fs,
                                                   ws + Q_OFF, ck, cv);
  attn_part_k<<<NB * NSPLIT, 512, 0, stream>>>(ws + Q_OFF, ck, cv,
                                               ws + PML_OFF, ws + PO_OFF);
  attn_comb_k<<<(NB * DIM) / 256, 256, 0, stream>>>(ws + PML_OFF, ws + PO_OFF, ws + ATTN_OFF);
  wo_k<<<DIM / 4, 128, 0, stream>>>(ws + ATTN_OFF, wo, x, ws + H_OFF);
  rmsnorm_k<<<NB, 256, 0, stream>>>(ws + H_OFF, fnw, ws + HN_OFF);
  ffn13_k<<<(FFH + DIM) / 4, 128, 0, stream>>>(ws + HN_OFF, w1, w3, ws + H1_OFF, ws + H3_OFF);
  ffn2_k<<<DIM / 4, 128, 0, stream>>>(ws + H1_OFF, w2, ws + H_OFF, ws + H3_OFF, out);
}